// Round 5
// baseline (5346.991 us; speedup 1.0000x reference)
//
#include <hip/hip_runtime.h>
#include <stdint.h>

// ============================================================================
// LSTM stack, batch-sliced: reference returns out[:, -1] == batch element 255
// only -> single sequence (T=512) through 4 layers (H=256) + final linear.
//
// Round 5: hide cross-WG latency (poll + coherent data loads) under compute.
//   Round 4 exposed one L3 RTT (~1000cy) per step: the counter poll sat at the
//   loop top, serialized before prefetch+dots (consumer runs at producer rate
//   -> cached rdy always exhausted -> fresh L3 load every step).
//   Now: counter load ISSUED at loop top, CHECKED after the ~3000cy dot block
//   (s_waitcnt lands at the check -> hidden). xg folded into acc at the END so
//   the prefetch has a full dot-block of slack. proj prefetches h(t+1) into
//   regs at end of step t behind a hidden poll; releases before spinning.
// ============================================================================

typedef _Float16 half2v __attribute__((ext_vector_type(2)));

__device__ __forceinline__ float fdot2u(uint32_t w, uint32_t h, float acc) {
#if __has_builtin(__builtin_amdgcn_fdot2)
  return __builtin_amdgcn_fdot2(__builtin_bit_cast(half2v, w),
                                __builtin_bit_cast(half2v, h), acc, false);
#else
  half2v wv = __builtin_bit_cast(half2v, w);
  half2v hv = __builtin_bit_cast(half2v, h);
  acc += (float)wv[0] * (float)hv[0];
  acc += (float)wv[1] * (float)hv[1];
  return acc;
#endif
}

__device__ __forceinline__ float sigmoidf_(float x) {
  return 1.f / (1.f + __expf(-x));
}
__device__ __forceinline__ float tanhf_(float x) {
  return 1.f - 2.f / (__expf(2.f * x) + 1.f);  // exp overflow -> returns 1
}

#define CNT_STRIDE 32  // ints per counter slot = 128 B = 1 cacheline

__device__ __forceinline__ int cnt_load(const int* p) {
  return __hip_atomic_load(p, __ATOMIC_RELAXED, __HIP_MEMORY_SCOPE_AGENT);
}
__device__ __forceinline__ void cnt_store(int* p, int v) {
  __hip_atomic_store(p, v, __ATOMIC_RELAXED, __HIP_MEMORY_SCOPE_AGENT);
}
// device-coherent (sc0 sc1) data accesses -- no cache maintenance
__device__ __forceinline__ float ldg_f32(const float* p) {
  uint32_t u = __hip_atomic_load((const uint32_t*)p, __ATOMIC_RELAXED,
                                 __HIP_MEMORY_SCOPE_AGENT);
  return __builtin_bit_cast(float, u);
}
__device__ __forceinline__ void stg_f32(float* p, float v) {
  __hip_atomic_store((uint32_t*)p, __builtin_bit_cast(uint32_t, v),
                     __ATOMIC_RELAXED, __HIP_MEMORY_SCOPE_AGENT);
}
__device__ __forceinline__ uint64_t ldg_u64(const float* p) {
  return __hip_atomic_load((const uint64_t*)p, __ATOMIC_RELAXED,
                           __HIP_MEMORY_SCOPE_AGENT);
}

// spin until *p >= need; rdy caches the last observed value (monotone counter)
__device__ __forceinline__ void wait_ge(const int* p, int need, int& rdy) {
  while (rdy < need) {
    rdy = cnt_load(p);
    if (rdy < need) __builtin_amdgcn_s_sleep(1);
  }
  asm volatile("" ::: "memory");  // keep data loads below the poll (compiler)
}

__global__ void zero_cnt(int* c) {
  if (threadIdx.x < 16 * CNT_STRIDE) c[threadIdx.x] = 0;
}

// ---- pack a 1024x256 f32 matrix into u32 of 2xfp16: out[r*128+k2]
__global__ __launch_bounds__(256) void pack_whh(const float* __restrict__ w,
                                                uint32_t* __restrict__ wpk) {
  int idx = blockIdx.x * 256 + threadIdx.x;  // 0 .. 131071
  int r = idx >> 7, k2 = idx & 127;
  float f0 = w[r * 256 + 2 * k2];
  float f1 = w[r * 256 + 2 * k2 + 1];
  union { _Float16 h; uint16_t u; } a, b;
  a.h = (_Float16)f0;
  b.h = (_Float16)f1;
  wpk[idx] = (uint32_t)a.u | ((uint32_t)b.u << 16);
}

// ---- layer-0 input projection (from x, fully parallel, f32)
__global__ __launch_bounds__(256) void proj_gemm(const float* __restrict__ in, int istride, int K,
                                                 const float* __restrict__ W,
                                                 const float* __restrict__ bih,
                                                 const float* __restrict__ bhh,
                                                 float* __restrict__ xg) {
  __shared__ float xs[8][512];
  const int tid = threadIdx.x;
  const int r = blockIdx.x * 256 + tid;
  const int t0 = blockIdx.y * 8;
  for (int tt = 0; tt < 8; ++tt)
    for (int k = tid; k < K; k += 256)
      xs[tt][k] = in[(size_t)(t0 + tt) * istride + k];
  __syncthreads();
  float bias = bih[r] + bhh[r];
  float acc[8];
#pragma unroll
  for (int j = 0; j < 8; ++j) acc[j] = bias;
  const float* wr = W + (size_t)r * K;
  for (int k = 0; k < K; k += 4) {
    float4 w4 = *reinterpret_cast<const float4*>(wr + k);
#pragma unroll
    for (int j = 0; j < 8; ++j)
      acc[j] += xs[j][k] * w4.x + xs[j][k + 1] * w4.y + xs[j][k + 2] * w4.z +
                xs[j][k + 3] * w4.w;
  }
#pragma unroll
  for (int j = 0; j < 8; ++j) xg[(size_t)(t0 + j) * 1024 + r] = acc[j];
}

// ============================ pipeline stages ===============================

// scan: 512 thr; thread 2j: rows (j, j+256); thread 2j+1: rows (j+512, j+768)
__device__ void scan_fn(int l, const uint32_t* __restrict__ wpk,
                        const float* __restrict__ xgsrc,
                        float* __restrict__ hseq, int* __restrict__ cnt) {
  __shared__ __align__(16) uint4 wlds[8 * 2 * 512];   // 128 KB
  __shared__ __align__(16) uint16_t hbuf[2][256];
  const int tid = threadIdx.x;
  const int j = tid >> 1;
  const int odd = tid & 1;
  const int rA = j + (odd ? 512 : 0);
  const int rB = rA + 256;

  uint32_t wA[96], wB[96];
  {
    const uint4* gA = reinterpret_cast<const uint4*>(wpk + rA * 128);
    const uint4* gB = reinterpret_cast<const uint4*>(wpk + rB * 128);
#pragma unroll
    for (int q = 0; q < 24; ++q) {
      uint4 a = gA[q];
      wA[4 * q + 0] = a.x; wA[4 * q + 1] = a.y; wA[4 * q + 2] = a.z; wA[4 * q + 3] = a.w;
      uint4 b = gB[q];
      wB[4 * q + 0] = b.x; wB[4 * q + 1] = b.y; wB[4 * q + 2] = b.z; wB[4 * q + 3] = b.w;
    }
#pragma unroll
    for (int c = 0; c < 8; ++c) {
      wlds[(c * 2 + 0) * 512 + tid] = gA[24 + c];
      wlds[(c * 2 + 1) * 512 + tid] = gB[24 + c];
    }
  }
  if (tid < 256) hbuf[0][tid] = 0;
  __syncthreads();

  const int* mycnt = &cnt[(4 + (l - 1) * 2 + odd) * CNT_STRIDE];
  int rdy = 0;
  if (l) wait_ge(mycnt, 1, rdy);
  float c_ = 0.f;
  float xga = ldg_f32(xgsrc + rA), xgb = ldg_f32(xgsrc + rB);
  int pp = 0;
  for (int t = 0; t < 512; ++t) {
    const int tn = (t < 511) ? (t + 1) : 511;
    const int need = (t + 2 > 512) ? 512 : (t + 2);
    // EARLY-ISSUE the counter load; s_waitcnt lands at the check below,
    // ~3000cy later -> L3 latency hidden under the dot block.
    int fut = rdy;
    if (l && rdy < need) fut = cnt_load(mycnt);

    float accA0 = 0.f, accA1 = 0.f, accB0 = 0.f, accB1 = 0.f;
    const uint4* hv4 = reinterpret_cast<const uint4*>(&hbuf[pp][0]);
#pragma unroll
    for (int ch = 0; ch < 24; ++ch) {
      uint4 h4 = hv4[ch];
      accA0 = fdot2u(wA[4 * ch + 0], h4.x, accA0);
      accA1 = fdot2u(wA[4 * ch + 1], h4.y, accA1);
      accA0 = fdot2u(wA[4 * ch + 2], h4.z, accA0);
      accA1 = fdot2u(wA[4 * ch + 3], h4.w, accA1);
      accB0 = fdot2u(wB[4 * ch + 0], h4.x, accB0);
      accB1 = fdot2u(wB[4 * ch + 1], h4.y, accB1);
      accB0 = fdot2u(wB[4 * ch + 2], h4.z, accB0);
      accB1 = fdot2u(wB[4 * ch + 3], h4.w, accB1);
    }
#pragma unroll
    for (int cc = 0; cc < 8; ++cc) {
      uint4 h4 = hv4[24 + cc];
      uint4 wa = wlds[(cc * 2 + 0) * 512 + tid];
      uint4 wb = wlds[(cc * 2 + 1) * 512 + tid];
      accA0 = fdot2u(wa.x, h4.x, accA0);
      accA1 = fdot2u(wa.y, h4.y, accA1);
      accA0 = fdot2u(wa.z, h4.z, accA0);
      accA1 = fdot2u(wa.w, h4.w, accA1);
      accB0 = fdot2u(wb.x, h4.x, accB0);
      accB1 = fdot2u(wb.y, h4.y, accB1);
      accB0 = fdot2u(wb.z, h4.z, accB0);
      accB1 = fdot2u(wb.w, h4.w, accB1);
    }
    // fold xg in at the END: the prefetch issued below has a full dot block
    // of slack before first use (next iteration's fold).
    float accA = accA0 + accA1 + xga;
    float accB = accB0 + accB1 + xgb;

    if (l) {  // check (usually satisfied by fut), spin only on miss
      if (fut > rdy) rdy = fut;
      while (rdy < need) {
        rdy = cnt_load(mycnt);
        if (rdy < need) __builtin_amdgcn_s_sleep(1);
      }
      asm volatile("" ::: "memory");
    }
    float nxa = ldg_f32(xgsrc + tn * 1024 + rA);  // prefetch t+1
    float nxb = ldg_f32(xgsrc + tn * 1024 + rB);

    float o0 = __shfl_xor(accA, 1);
    float o1 = __shfl_xor(accB, 1);
    float pi = odd ? o0 : accA;
    float pf = odd ? o1 : accB;
    float pg = odd ? accA : o0;
    float po = odd ? accB : o1;

    c_ = sigmoidf_(pf) * c_ + sigmoidf_(pi) * tanhf_(pg);
    float h = sigmoidf_(po) * tanhf_(c_);
    if (!odd) {
      stg_f32(hseq + t * 256 + j, h);  // device-coherent store
      union { _Float16 hf; uint16_t u; } cv;
      cv.hf = (_Float16)h;
      hbuf[pp ^ 1][j] = cv.u;
    }
    __syncthreads();  // all waves drain vmcnt(0) -> h stores at coherence point
    if (tid == 0) cnt_store(&cnt[l * CNT_STRIDE], t + 1);
    pp ^= 1;
    xga = nxa;
    xgb = nxb;
  }
}

// proj: 512 thr, WG owns rows [half*512, half*512+512). 1 row/thread.
// h(t+1) register-prefetched at end of step t behind a hidden early poll.
__device__ void proj_fn(int l, int half, const uint32_t* __restrict__ wpk,
                        const float* __restrict__ bih, const float* __restrict__ bhh,
                        const float* __restrict__ hsrc,   // hseq layer l-1 (f32)
                        float* __restrict__ xgdst, int* __restrict__ cnt) {
  __shared__ __align__(16) uint32_t hpk[128];  // h as packed fp16 pairs
  const int tid = threadIdx.x;
  const int row = half * 512 + tid;

  uint32_t wr_[128];
  {
    const uint4* g = reinterpret_cast<const uint4*>(wpk + (size_t)row * 128);
#pragma unroll
    for (int q = 0; q < 32; ++q) {
      uint4 v = g[q];
      wr_[4 * q + 0] = v.x; wr_[4 * q + 1] = v.y; wr_[4 * q + 2] = v.z; wr_[4 * q + 3] = v.w;
    }
  }
  const float bias = bih[row] + bhh[row];
  const int* prev = &cnt[(l - 1) * CNT_STRIDE];
  int* mine = &cnt[(4 + (l - 1) * 2 + half) * CNT_STRIDE];
  int rdy = 0;

  wait_ge(prev, 1, rdy);
  uint64_t hv = 0;
  if (tid < 128) hv = ldg_u64(hsrc + 2 * tid);  // h(0)

  for (int t = 0; t < 512; ++t) {
    if (tid < 128) {
      float hx = __builtin_bit_cast(float, (uint32_t)hv);
      float hy = __builtin_bit_cast(float, (uint32_t)(hv >> 32));
      union { _Float16 h; uint16_t u; } a, b;
      a.h = (_Float16)hx;
      b.h = (_Float16)hy;
      hpk[tid] = (uint32_t)a.u | ((uint32_t)b.u << 16);
    }
    __syncthreads();  // h staged

    // early-issue poll for h(t+1); checked after the dots (hidden)
    int fut = rdy;
    if (t < 511 && rdy < t + 2) fut = cnt_load(prev);

    float a0 = bias, a1 = 0.f;
    const uint4* hv4 = reinterpret_cast<const uint4*>(hpk);
#pragma unroll
    for (int q = 0; q < 32; ++q) {
      uint4 h4 = hv4[q];
      a0 = fdot2u(wr_[4 * q + 0], h4.x, a0);
      a1 = fdot2u(wr_[4 * q + 1], h4.y, a1);
      a0 = fdot2u(wr_[4 * q + 2], h4.z, a0);
      a1 = fdot2u(wr_[4 * q + 3], h4.w, a1);
    }
    stg_f32(xgdst + t * 1024 + row, a0 + a1);  // device-coherent store
    __syncthreads();  // xg stores drained; hpk reads done before next overwrite
    if (tid == 0) cnt_store(mine, t + 1);  // release BEFORE next-step spin

    if (t < 511) {
      if (fut > rdy) rdy = fut;
      while (rdy < t + 2) {
        rdy = cnt_load(prev);
        if (rdy < t + 2) __builtin_amdgcn_s_sleep(1);
      }
      asm volatile("" ::: "memory");
      if (tid < 128) hv = ldg_u64(hsrc + (t + 1) * 256 + 2 * tid);  // h(t+1)
    }
  }
}

// grid.x = 10: 0=scan0 | 1,2=proj1 | 3=scan1 | 4,5=proj2 | 6=scan2 | 7,8=proj3 | 9=scan3
__global__ __launch_bounds__(512, 2) void pipeline(
    const uint32_t* __restrict__ wpkhh, const uint32_t* __restrict__ wpkih,
    const float* __restrict__ xg0, float* __restrict__ xgp,
    float* __restrict__ hseq,
    const float* __restrict__ bih1, const float* __restrict__ bhh1,
    const float* __restrict__ bih2, const float* __restrict__ bhh2,
    const float* __restrict__ bih3, const float* __restrict__ bhh3,
    int* __restrict__ cnt) {
  const int bx = blockIdx.x;
  if (bx == 0) {
    scan_fn(0, wpkhh, xg0, hseq, cnt);
  } else {
    const int g = bx - 1;
    const int l = g / 3 + 1;
    const int r = g % 3;
    const float* bih = (l == 1) ? bih1 : (l == 2) ? bih2 : bih3;
    const float* bhh = (l == 1) ? bhh1 : (l == 2) ? bhh2 : bhh3;
    if (r < 2)
      proj_fn(l, r, wpkih + (size_t)(l - 1) * 131072, bih, bhh,
              hseq + (size_t)(l - 1) * 131072, xgp + (size_t)(l - 1) * 524288, cnt);
    else
      scan_fn(l, wpkhh + (size_t)l * 131072, xgp + (size_t)(l - 1) * 524288,
              hseq + (size_t)l * 131072, cnt);
  }
}

// ---- final linear
__global__ __launch_bounds__(256) void final_gemm(const float* __restrict__ h3,
                                                  const float* __restrict__ lrw,
                                                  const float* __restrict__ lrb,
                                                  float* __restrict__ out) {
  __shared__ float xs[8][256];
  const int j = threadIdx.x;
  const int t0 = blockIdx.x * 8;
  for (int tt = 0; tt < 8; ++tt) xs[tt][j] = h3[(t0 + tt) * 256 + j];
  __syncthreads();
  float bias = lrb[j];
  float acc[8];
#pragma unroll
  for (int jj = 0; jj < 8; ++jj) acc[jj] = bias;
  const float* wr = lrw + j * 256;
  for (int k = 0; k < 256; k += 4) {
    float4 w4 = *reinterpret_cast<const float4*>(wr + k);
#pragma unroll
    for (int jj = 0; jj < 8; ++jj)
      acc[jj] += xs[jj][k] * w4.x + xs[jj][k + 1] * w4.y + xs[jj][k + 2] * w4.z +
                 xs[jj][k + 3] * w4.w;
  }
#pragma unroll
  for (int jj = 0; jj < 8; ++jj) out[(t0 + jj) * 256 + j] = acc[jj];
}

extern "C" void kernel_launch(void* const* d_in, const int* in_sizes, int n_in,
                              void* d_out, int out_size, void* d_ws, size_t ws_size,
                              hipStream_t stream) {
  (void)in_sizes; (void)n_in; (void)out_size; (void)ws_size;
  const float* x = (const float*)d_in[0];
  const float* wih[4] = {(const float*)d_in[1], (const float*)d_in[5],
                         (const float*)d_in[9], (const float*)d_in[13]};
  const float* whh[4] = {(const float*)d_in[2], (const float*)d_in[6],
                         (const float*)d_in[10], (const float*)d_in[14]};
  const float* bih[4] = {(const float*)d_in[3], (const float*)d_in[7],
                         (const float*)d_in[11], (const float*)d_in[15]};
  const float* bhh[4] = {(const float*)d_in[4], (const float*)d_in[8],
                         (const float*)d_in[12], (const float*)d_in[16]};
  const float* lrw = (const float*)d_in[17];
  const float* lrb = (const float*)d_in[18];
  float* out = (float*)d_out;

  // ws layout (4B units):
  //   xg0[524288] | xgp[3*524288] | hseq[4*131072] | wpkhh u32[4*131072]
  //   | wpkih u32[3*131072] | cnt int[16*CNT_STRIDE]      (~14.2 MB total)
  float* ws = (float*)d_ws;
  float* xg0 = ws;
  float* xgp = ws + 524288;
  float* hseq = xgp + 3 * 524288;
  uint32_t* wpkhh = (uint32_t*)(hseq + 4 * 131072);
  uint32_t* wpkih = wpkhh + 4 * 131072;
  int* cnt = (int*)(wpkih + 3 * 131072);

  zero_cnt<<<1, 512, 0, stream>>>(cnt);
  for (int l = 0; l < 4; ++l)
    pack_whh<<<512, 256, 0, stream>>>(whh[l], wpkhh + (size_t)l * 131072);
  for (int l = 1; l < 4; ++l)
    pack_whh<<<512, 256, 0, stream>>>(wih[l], wpkih + (size_t)(l - 1) * 131072);

  // layer-0 projection from x (batch element 255)
  proj_gemm<<<dim3(4, 64), 256, 0, stream>>>(x + 255 * 512, 256 * 512, 512,
                                             wih[0], bih[0], bhh[0], xg0);

  pipeline<<<10, 512, 0, stream>>>(wpkhh, wpkih, xg0, xgp, hseq,
                                   bih[1], bhh[1], bih[2], bhh[2], bih[3], bhh[3],
                                   cnt);

  final_gemm<<<64, 256, 0, stream>>>(hseq + 3 * 131072, lrw, lrb, out);
}

// Round 6
// 1228.913 us; speedup vs baseline: 4.3510x; 4.3510x over previous
//
#include <hip/hip_runtime.h>
#include <stdint.h>

// ============================================================================
// LSTM stack, batch-sliced: reference returns out[:, -1] == batch element 255
// only -> single sequence (T=512) through 4 layers (H=256) + final linear.
//
// Round 6 = round 4 (proven 1103us pipeline) + two surgical sync fixes:
//   (1) delayed h-store: scan stores h(t-1) at TOP of step t, so the
//       __syncthreads vmcnt(0) drain sees a ~3000cy-old store (was ~100cy
//       -> ~800cy exposed ack-to-coherence-point per step). Publish value
//       becomes t ("h(0..t-1) ready") -- same semantics, consumers unchanged.
//   (2) startup slack: scan pre-waits mycnt>=8, proj pre-waits prev>=4.
//       Producer builds an ~8-step lead during the delayed start and keeps it
//       (equal steady rates) -> cached rdy amortizes the poll RTT to ~1/7
//       steps instead of every step.
//   Inner dot loops and proj body byte-identical to round 4 (round-5 lesson:
//   do NOT restructure the proven loop around atomics/inline asm).
// ============================================================================

typedef _Float16 half2v __attribute__((ext_vector_type(2)));

__device__ __forceinline__ float fdot2u(uint32_t w, uint32_t h, float acc) {
#if __has_builtin(__builtin_amdgcn_fdot2)
  return __builtin_amdgcn_fdot2(__builtin_bit_cast(half2v, w),
                                __builtin_bit_cast(half2v, h), acc, false);
#else
  half2v wv = __builtin_bit_cast(half2v, w);
  half2v hv = __builtin_bit_cast(half2v, h);
  acc += (float)wv[0] * (float)hv[0];
  acc += (float)wv[1] * (float)hv[1];
  return acc;
#endif
}

__device__ __forceinline__ float sigmoidf_(float x) {
  return 1.f / (1.f + __expf(-x));
}
__device__ __forceinline__ float tanhf_(float x) {
  return 1.f - 2.f / (__expf(2.f * x) + 1.f);  // exp overflow -> returns 1
}

#define CNT_STRIDE 32  // ints per counter slot = 128 B = 1 cacheline

__device__ __forceinline__ int cnt_load(const int* p) {
  return __hip_atomic_load(p, __ATOMIC_RELAXED, __HIP_MEMORY_SCOPE_AGENT);
}
__device__ __forceinline__ void cnt_store(int* p, int v) {
  __hip_atomic_store(p, v, __ATOMIC_RELAXED, __HIP_MEMORY_SCOPE_AGENT);
}
// device-coherent (sc0 sc1) data accesses -- no cache maintenance
__device__ __forceinline__ float ldg_f32(const float* p) {
  uint32_t u = __hip_atomic_load((const uint32_t*)p, __ATOMIC_RELAXED,
                                 __HIP_MEMORY_SCOPE_AGENT);
  return __builtin_bit_cast(float, u);
}
__device__ __forceinline__ void stg_f32(float* p, float v) {
  __hip_atomic_store((uint32_t*)p, __builtin_bit_cast(uint32_t, v),
                     __ATOMIC_RELAXED, __HIP_MEMORY_SCOPE_AGENT);
}
__device__ __forceinline__ uint64_t ldg_u64(const float* p) {
  return __hip_atomic_load((const uint64_t*)p, __ATOMIC_RELAXED,
                           __HIP_MEMORY_SCOPE_AGENT);
}

// spin until *p >= need; rdy caches the last observed value (monotone counter)
__device__ __forceinline__ void wait_ge(const int* p, int need, int& rdy) {
  while (rdy < need) {
    rdy = cnt_load(p);
    if (rdy < need) __builtin_amdgcn_s_sleep(2);
  }
  asm volatile("" ::: "memory");  // keep data loads below the poll (compiler)
}

__global__ void zero_cnt(int* c) {
  if (threadIdx.x < 16 * CNT_STRIDE) c[threadIdx.x] = 0;
}

// ---- pack a 1024x256 f32 matrix into u32 of 2xfp16: out[r*128+k2]
__global__ __launch_bounds__(256) void pack_whh(const float* __restrict__ w,
                                                uint32_t* __restrict__ wpk) {
  int idx = blockIdx.x * 256 + threadIdx.x;  // 0 .. 131071
  int r = idx >> 7, k2 = idx & 127;
  float f0 = w[r * 256 + 2 * k2];
  float f1 = w[r * 256 + 2 * k2 + 1];
  union { _Float16 h; uint16_t u; } a, b;
  a.h = (_Float16)f0;
  b.h = (_Float16)f1;
  wpk[idx] = (uint32_t)a.u | ((uint32_t)b.u << 16);
}

// ---- layer-0 input projection (from x, fully parallel, f32)
__global__ __launch_bounds__(256) void proj_gemm(const float* __restrict__ in, int istride, int K,
                                                 const float* __restrict__ W,
                                                 const float* __restrict__ bih,
                                                 const float* __restrict__ bhh,
                                                 float* __restrict__ xg) {
  __shared__ float xs[8][512];
  const int tid = threadIdx.x;
  const int r = blockIdx.x * 256 + tid;
  const int t0 = blockIdx.y * 8;
  for (int tt = 0; tt < 8; ++tt)
    for (int k = tid; k < K; k += 256)
      xs[tt][k] = in[(size_t)(t0 + tt) * istride + k];
  __syncthreads();
  float bias = bih[r] + bhh[r];
  float acc[8];
#pragma unroll
  for (int j = 0; j < 8; ++j) acc[j] = bias;
  const float* wr = W + (size_t)r * K;
  for (int k = 0; k < K; k += 4) {
    float4 w4 = *reinterpret_cast<const float4*>(wr + k);
#pragma unroll
    for (int j = 0; j < 8; ++j)
      acc[j] += xs[j][k] * w4.x + xs[j][k + 1] * w4.y + xs[j][k + 2] * w4.z +
                xs[j][k + 3] * w4.w;
  }
#pragma unroll
  for (int j = 0; j < 8; ++j) xg[(size_t)(t0 + j) * 1024 + r] = acc[j];
}

// ============================ pipeline stages ===============================

// scan: 512 thr; thread 2j: rows (j, j+256); thread 2j+1: rows (j+512, j+768)
// Counter semantics: cnt[l] == v  <=>  h(0..v-1) stored & visible.
__device__ void scan_fn(int l, const uint32_t* __restrict__ wpk,
                        const float* __restrict__ xgsrc,
                        float* __restrict__ hseq, int* __restrict__ cnt) {
  __shared__ __align__(16) uint4 wlds[8 * 2 * 512];   // 128 KB
  __shared__ __align__(16) uint16_t hbuf[2][256];
  const int tid = threadIdx.x;
  const int j = tid >> 1;
  const int odd = tid & 1;
  const int rA = j + (odd ? 512 : 0);
  const int rB = rA + 256;

  uint32_t wA[96], wB[96];
  {
    const uint4* gA = reinterpret_cast<const uint4*>(wpk + rA * 128);
    const uint4* gB = reinterpret_cast<const uint4*>(wpk + rB * 128);
#pragma unroll
    for (int q = 0; q < 24; ++q) {
      uint4 a = gA[q];
      wA[4 * q + 0] = a.x; wA[4 * q + 1] = a.y; wA[4 * q + 2] = a.z; wA[4 * q + 3] = a.w;
      uint4 b = gB[q];
      wB[4 * q + 0] = b.x; wB[4 * q + 1] = b.y; wB[4 * q + 2] = b.z; wB[4 * q + 3] = b.w;
    }
#pragma unroll
    for (int c = 0; c < 8; ++c) {
      wlds[(c * 2 + 0) * 512 + tid] = gA[24 + c];
      wlds[(c * 2 + 1) * 512 + tid] = gB[24 + c];
    }
  }
  if (tid < 256) hbuf[0][tid] = 0;
  __syncthreads();

  const int* mycnt = &cnt[(4 + (l - 1) * 2 + odd) * CNT_STRIDE];
  int rdy = 0;
  if (l) wait_ge(mycnt, 8, rdy);  // startup slack: build ~8-step producer lead
  float c_ = 0.f;
  float xga = ldg_f32(xgsrc + rA), xgb = ldg_f32(xgsrc + rB);
  float hprev = 0.f;  // h(t-1), stored one step late (even threads)
  int pp = 0;
  for (int t = 0; t < 512; ++t) {
    const int tn = (t < 511) ? (t + 1) : 511;
    if (l) {
      int need = (t + 2 > 512) ? 512 : (t + 2);
      wait_ge(mycnt, need, rdy);  // cached rdy: ~1 real poll per ~7 steps
    }
    // delayed h-store: issued a full dot block before this step's barrier,
    // so the barrier's vmcnt(0) drain sees an already-acked store.
    if (!odd && t > 0) stg_f32(hseq + (t - 1) * 256 + j, hprev);
    float nxa = ldg_f32(xgsrc + tn * 1024 + rA);  // prefetch t+1
    float nxb = ldg_f32(xgsrc + tn * 1024 + rB);

    float accA0 = xga, accA1 = 0.f, accB0 = xgb, accB1 = 0.f;
    const uint4* hv4 = reinterpret_cast<const uint4*>(&hbuf[pp][0]);
#pragma unroll
    for (int ch = 0; ch < 24; ++ch) {
      uint4 h4 = hv4[ch];
      accA0 = fdot2u(wA[4 * ch + 0], h4.x, accA0);
      accA1 = fdot2u(wA[4 * ch + 1], h4.y, accA1);
      accA0 = fdot2u(wA[4 * ch + 2], h4.z, accA0);
      accA1 = fdot2u(wA[4 * ch + 3], h4.w, accA1);
      accB0 = fdot2u(wB[4 * ch + 0], h4.x, accB0);
      accB1 = fdot2u(wB[4 * ch + 1], h4.y, accB1);
      accB0 = fdot2u(wB[4 * ch + 2], h4.z, accB0);
      accB1 = fdot2u(wB[4 * ch + 3], h4.w, accB1);
    }
#pragma unroll
    for (int cc = 0; cc < 8; ++cc) {
      uint4 h4 = hv4[24 + cc];
      uint4 wa = wlds[(cc * 2 + 0) * 512 + tid];
      uint4 wb = wlds[(cc * 2 + 1) * 512 + tid];
      accA0 = fdot2u(wa.x, h4.x, accA0);
      accA1 = fdot2u(wa.y, h4.y, accA1);
      accA0 = fdot2u(wa.z, h4.z, accA0);
      accA1 = fdot2u(wa.w, h4.w, accA1);
      accB0 = fdot2u(wb.x, h4.x, accB0);
      accB1 = fdot2u(wb.y, h4.y, accB1);
      accB0 = fdot2u(wb.z, h4.z, accB0);
      accB1 = fdot2u(wb.w, h4.w, accB1);
    }
    float accA = accA0 + accA1;
    float accB = accB0 + accB1;

    float o0 = __shfl_xor(accA, 1);
    float o1 = __shfl_xor(accB, 1);
    float pi = odd ? o0 : accA;
    float pf = odd ? o1 : accB;
    float pg = odd ? accA : o0;
    float po = odd ? accB : o1;

    c_ = sigmoidf_(pf) * c_ + sigmoidf_(pi) * tanhf_(pg);
    float h = sigmoidf_(po) * tanhf_(c_);
    if (!odd) {
      union { _Float16 hf; uint16_t u; } cv;
      cv.hf = (_Float16)h;
      hbuf[pp ^ 1][j] = cv.u;
    }
    hprev = h;
    __syncthreads();  // drains old h(t-1) store acks (cheap) + hbuf visible
    if (tid == 0) cnt_store(&cnt[l * CNT_STRIDE], t);  // h(0..t-1) ready
    pp ^= 1;
    xga = nxa;
    xgb = nxb;
  }
  // epilogue: final h(511) store, drain, publish 512
  if (!odd) stg_f32(hseq + 511 * 256 + j, hprev);
  __syncthreads();  // vmcnt(0): h(511) acked at coherence point
  if (tid == 0) cnt_store(&cnt[l * CNT_STRIDE], 512);
}

// proj: 512 thr, WG owns rows [half*512, half*512+512). 1 row/thread.
// Body identical to round 4; only the pre-loop slack wait added.
__device__ void proj_fn(int l, int half, const uint32_t* __restrict__ wpk,
                        const float* __restrict__ bih, const float* __restrict__ bhh,
                        const float* __restrict__ hsrc,   // hseq layer l-1 (f32)
                        float* __restrict__ xgdst, int* __restrict__ cnt) {
  __shared__ __align__(16) uint32_t hpk[128];  // h as packed fp16 pairs
  const int tid = threadIdx.x;
  const int row = half * 512 + tid;

  uint32_t wr_[128];
  {
    const uint4* g = reinterpret_cast<const uint4*>(wpk + (size_t)row * 128);
#pragma unroll
    for (int q = 0; q < 32; ++q) {
      uint4 v = g[q];
      wr_[4 * q + 0] = v.x; wr_[4 * q + 1] = v.y; wr_[4 * q + 2] = v.z; wr_[4 * q + 3] = v.w;
    }
  }
  const float bias = bih[row] + bhh[row];
  const int* prev = &cnt[(l - 1) * CNT_STRIDE];
  int* mine = &cnt[(4 + (l - 1) * 2 + half) * CNT_STRIDE];
  int rdy = 0;
  wait_ge(prev, 4, rdy);  // startup slack: ~4-step upstream lead

  for (int t = 0; t < 512; ++t) {
    wait_ge(prev, t + 1, rdy);
    if (tid < 128) {
      uint64_t hv = ldg_u64(hsrc + t * 256 + 2 * tid);  // device-coherent 8B
      float hx = __builtin_bit_cast(float, (uint32_t)hv);
      float hy = __builtin_bit_cast(float, (uint32_t)(hv >> 32));
      union { _Float16 h; uint16_t u; } a, b;
      a.h = (_Float16)hx;
      b.h = (_Float16)hy;
      hpk[tid] = (uint32_t)a.u | ((uint32_t)b.u << 16);
    }
    __syncthreads();  // h staged
    float a0 = bias, a1 = 0.f;
    const uint4* hv4 = reinterpret_cast<const uint4*>(hpk);
#pragma unroll
    for (int q = 0; q < 32; ++q) {
      uint4 h4 = hv4[q];
      a0 = fdot2u(wr_[4 * q + 0], h4.x, a0);
      a1 = fdot2u(wr_[4 * q + 1], h4.y, a1);
      a0 = fdot2u(wr_[4 * q + 2], h4.z, a0);
      a1 = fdot2u(wr_[4 * q + 3], h4.w, a1);
    }
    stg_f32(xgdst + t * 1024 + row, a0 + a1);  // device-coherent store
    __syncthreads();  // xg stores drained; hpk reads done before next overwrite
    if (tid == 0) cnt_store(mine, t + 1);  // xg(0..t) ready
  }
}

// grid.x = 10: 0=scan0 | 1,2=proj1 | 3=scan1 | 4,5=proj2 | 6=scan2 | 7,8=proj3 | 9=scan3
__global__ __launch_bounds__(512, 2) void pipeline(
    const uint32_t* __restrict__ wpkhh, const uint32_t* __restrict__ wpkih,
    const float* __restrict__ xg0, float* __restrict__ xgp,
    float* __restrict__ hseq,
    const float* __restrict__ bih1, const float* __restrict__ bhh1,
    const float* __restrict__ bih2, const float* __restrict__ bhh2,
    const float* __restrict__ bih3, const float* __restrict__ bhh3,
    int* __restrict__ cnt) {
  const int bx = blockIdx.x;
  if (bx == 0) {
    scan_fn(0, wpkhh, xg0, hseq, cnt);
  } else {
    const int g = bx - 1;
    const int l = g / 3 + 1;
    const int r = g % 3;
    const float* bih = (l == 1) ? bih1 : (l == 2) ? bih2 : bih3;
    const float* bhh = (l == 1) ? bhh1 : (l == 2) ? bhh2 : bhh3;
    if (r < 2)
      proj_fn(l, r, wpkih + (size_t)(l - 1) * 131072, bih, bhh,
              hseq + (size_t)(l - 1) * 131072, xgp + (size_t)(l - 1) * 524288, cnt);
    else
      scan_fn(l, wpkhh + (size_t)l * 131072, xgp + (size_t)(l - 1) * 524288,
              hseq + (size_t)l * 131072, cnt);
  }
}

// ---- final linear
__global__ __launch_bounds__(256) void final_gemm(const float* __restrict__ h3,
                                                  const float* __restrict__ lrw,
                                                  const float* __restrict__ lrb,
                                                  float* __restrict__ out) {
  __shared__ float xs[8][256];
  const int j = threadIdx.x;
  const int t0 = blockIdx.x * 8;
  for (int tt = 0; tt < 8; ++tt) xs[tt][j] = h3[(t0 + tt) * 256 + j];
  __syncthreads();
  float bias = lrb[j];
  float acc[8];
#pragma unroll
  for (int jj = 0; jj < 8; ++jj) acc[jj] = bias;
  const float* wr = lrw + j * 256;
  for (int k = 0; k < 256; k += 4) {
    float4 w4 = *reinterpret_cast<const float4*>(wr + k);
#pragma unroll
    for (int jj = 0; jj < 8; ++jj)
      acc[jj] += xs[jj][k] * w4.x + xs[jj][k + 1] * w4.y + xs[jj][k + 2] * w4.z +
                 xs[jj][k + 3] * w4.w;
  }
#pragma unroll
  for (int jj = 0; jj < 8; ++jj) out[(t0 + jj) * 256 + j] = acc[jj];
}

extern "C" void kernel_launch(void* const* d_in, const int* in_sizes, int n_in,
                              void* d_out, int out_size, void* d_ws, size_t ws_size,
                              hipStream_t stream) {
  (void)in_sizes; (void)n_in; (void)out_size; (void)ws_size;
  const float* x = (const float*)d_in[0];
  const float* wih[4] = {(const float*)d_in[1], (const float*)d_in[5],
                         (const float*)d_in[9], (const float*)d_in[13]};
  const float* whh[4] = {(const float*)d_in[2], (const float*)d_in[6],
                         (const float*)d_in[10], (const float*)d_in[14]};
  const float* bih[4] = {(const float*)d_in[3], (const float*)d_in[7],
                         (const float*)d_in[11], (const float*)d_in[15]};
  const float* bhh[4] = {(const float*)d_in[4], (const float*)d_in[8],
                         (const float*)d_in[12], (const float*)d_in[16]};
  const float* lrw = (const float*)d_in[17];
  const float* lrb = (const float*)d_in[18];
  float* out = (float*)d_out;

  // ws layout (4B units):
  //   xg0[524288] | xgp[3*524288] | hseq[4*131072] | wpkhh u32[4*131072]
  //   | wpkih u32[3*131072] | cnt int[16*CNT_STRIDE]      (~14.2 MB total)
  float* ws = (float*)d_ws;
  float* xg0 = ws;
  float* xgp = ws + 524288;
  float* hseq = xgp + 3 * 524288;
  uint32_t* wpkhh = (uint32_t*)(hseq + 4 * 131072);
  uint32_t* wpkih = wpkhh + 4 * 131072;
  int* cnt = (int*)(wpkih + 3 * 131072);

  zero_cnt<<<1, 512, 0, stream>>>(cnt);
  for (int l = 0; l < 4; ++l)
    pack_whh<<<512, 256, 0, stream>>>(whh[l], wpkhh + (size_t)l * 131072);
  for (int l = 1; l < 4; ++l)
    pack_whh<<<512, 256, 0, stream>>>(wih[l], wpkih + (size_t)(l - 1) * 131072);

  // layer-0 projection from x (batch element 255)
  proj_gemm<<<dim3(4, 64), 256, 0, stream>>>(x + 255 * 512, 256 * 512, 512,
                                             wih[0], bih[0], bhh[0], xg0);

  pipeline<<<10, 512, 0, stream>>>(wpkhh, wpkih, xg0, xgp, hseq,
                                   bih[1], bhh[1], bih[2], bhh[2], bih[3], bhh[3],
                                   cnt);

  final_gemm<<<64, 256, 0, stream>>>(hseq + 3 * 131072, lrw, lrb, out);
}

// Round 7
// 1166.902 us; speedup vs baseline: 4.5822x; 1.0531x over previous
//
#include <hip/hip_runtime.h>
#include <stdint.h>

// ============================================================================
// LSTM stack, batch-sliced: reference returns out[:, -1] == batch element 255
// only -> single sequence (T=512) through 4 layers (H=256) + final linear.
//
// Round 7: proj was the rate limiter (~5200cy/step), not the scan.
//   - scan_fn: EXACT round-4 body (proven 1103us pipeline).
//   - proj_fn: 4-step chunks -> coherent-load RTT, store-drain RTT, barriers,
//     and poll amortize x4 (rate ~1800cy/step < scan 3960 -> scan-limited).
//   - final linear fused as 11th WG (streams cnt[3], f32 weights in regs,
//     2 thr/row + shfl_xor combine) -> no trailing dispatch.
//   - all 7 weight-pack launches merged into one pack_all kernel.
// ============================================================================

typedef _Float16 half2v __attribute__((ext_vector_type(2)));

__device__ __forceinline__ float fdot2u(uint32_t w, uint32_t h, float acc) {
#if __has_builtin(__builtin_amdgcn_fdot2)
  return __builtin_amdgcn_fdot2(__builtin_bit_cast(half2v, w),
                                __builtin_bit_cast(half2v, h), acc, false);
#else
  half2v wv = __builtin_bit_cast(half2v, w);
  half2v hv = __builtin_bit_cast(half2v, h);
  acc += (float)wv[0] * (float)hv[0];
  acc += (float)wv[1] * (float)hv[1];
  return acc;
#endif
}

__device__ __forceinline__ float sigmoidf_(float x) {
  return 1.f / (1.f + __expf(-x));
}
__device__ __forceinline__ float tanhf_(float x) {
  return 1.f - 2.f / (__expf(2.f * x) + 1.f);  // exp overflow -> returns 1
}

#define CNT_STRIDE 32  // ints per counter slot = 128 B = 1 cacheline

__device__ __forceinline__ int cnt_load(const int* p) {
  return __hip_atomic_load(p, __ATOMIC_RELAXED, __HIP_MEMORY_SCOPE_AGENT);
}
__device__ __forceinline__ void cnt_store(int* p, int v) {
  __hip_atomic_store(p, v, __ATOMIC_RELAXED, __HIP_MEMORY_SCOPE_AGENT);
}
// device-coherent (sc0 sc1) data accesses -- no cache maintenance
__device__ __forceinline__ float ldg_f32(const float* p) {
  uint32_t u = __hip_atomic_load((const uint32_t*)p, __ATOMIC_RELAXED,
                                 __HIP_MEMORY_SCOPE_AGENT);
  return __builtin_bit_cast(float, u);
}
__device__ __forceinline__ void stg_f32(float* p, float v) {
  __hip_atomic_store((uint32_t*)p, __builtin_bit_cast(uint32_t, v),
                     __ATOMIC_RELAXED, __HIP_MEMORY_SCOPE_AGENT);
}
__device__ __forceinline__ uint64_t ldg_u64(const float* p) {
  return __hip_atomic_load((const uint64_t*)p, __ATOMIC_RELAXED,
                           __HIP_MEMORY_SCOPE_AGENT);
}

// spin until *p >= need; rdy caches the last observed value (monotone counter)
__device__ __forceinline__ void wait_ge(const int* p, int need, int& rdy) {
  while (rdy < need) {
    rdy = cnt_load(p);
    if (rdy < need) __builtin_amdgcn_s_sleep(2);
  }
  asm volatile("" ::: "memory");  // keep data loads below the poll (compiler)
}

__global__ void zero_cnt(int* c) {
  if (threadIdx.x < 16 * CNT_STRIDE) c[threadIdx.x] = 0;
}

// ---- pack all 7 1024x256 f32 matrices into u32 of 2xfp16, one dispatch.
// dst layout: wpkhh[4][131072] | wpkih[3][131072] (contiguous).
__global__ __launch_bounds__(256) void pack_all(
    const float* __restrict__ w0, const float* __restrict__ w1,
    const float* __restrict__ w2, const float* __restrict__ w3,
    const float* __restrict__ w4, const float* __restrict__ w5,
    const float* __restrict__ w6, uint32_t* __restrict__ dst) {
  int b = blockIdx.x;           // 0..3583, 512 blocks per matrix
  int m = b >> 9;               // matrix id 0..6
  const float* src = (m == 0) ? w0 : (m == 1) ? w1 : (m == 2) ? w2
                   : (m == 3) ? w3 : (m == 4) ? w4 : (m == 5) ? w5 : w6;
  uint32_t* d = dst + (size_t)m * 131072;
  int idx = (b & 511) * 256 + threadIdx.x;  // 0 .. 131071
  int r = idx >> 7, k2 = idx & 127;
  float f0 = src[r * 256 + 2 * k2];
  float f1 = src[r * 256 + 2 * k2 + 1];
  union { _Float16 h; uint16_t u; } a, bb;
  a.h = (_Float16)f0;
  bb.h = (_Float16)f1;
  d[idx] = (uint32_t)a.u | ((uint32_t)bb.u << 16);
}

// ---- layer-0 input projection (from x, fully parallel, f32)
__global__ __launch_bounds__(256) void proj_gemm(const float* __restrict__ in, int istride, int K,
                                                 const float* __restrict__ W,
                                                 const float* __restrict__ bih,
                                                 const float* __restrict__ bhh,
                                                 float* __restrict__ xg) {
  __shared__ float xs[8][512];
  const int tid = threadIdx.x;
  const int r = blockIdx.x * 256 + tid;
  const int t0 = blockIdx.y * 8;
  for (int tt = 0; tt < 8; ++tt)
    for (int k = tid; k < K; k += 256)
      xs[tt][k] = in[(size_t)(t0 + tt) * istride + k];
  __syncthreads();
  float bias = bih[r] + bhh[r];
  float acc[8];
#pragma unroll
  for (int j = 0; j < 8; ++j) acc[j] = bias;
  const float* wr = W + (size_t)r * K;
  for (int k = 0; k < K; k += 4) {
    float4 w4 = *reinterpret_cast<const float4*>(wr + k);
#pragma unroll
    for (int j = 0; j < 8; ++j)
      acc[j] += xs[j][k] * w4.x + xs[j][k + 1] * w4.y + xs[j][k + 2] * w4.z +
                xs[j][k + 3] * w4.w;
  }
#pragma unroll
  for (int j = 0; j < 8; ++j) xg[(size_t)(t0 + j) * 1024 + r] = acc[j];
}

// ============================ pipeline stages ===============================

// scan: EXACT round-4 body. 512 thr; thread 2j: rows (j, j+256);
// thread 2j+1: rows (j+512, j+768). cnt[l]=v <=> h(0..v-1) visible.
__device__ void scan_fn(int l, const uint32_t* __restrict__ wpk,
                        const float* __restrict__ xgsrc,
                        float* __restrict__ hseq, int* __restrict__ cnt) {
  __shared__ __align__(16) uint4 wlds[8 * 2 * 512];   // 128 KB
  __shared__ __align__(16) uint16_t hbuf[2][256];
  const int tid = threadIdx.x;
  const int j = tid >> 1;
  const int odd = tid & 1;
  const int rA = j + (odd ? 512 : 0);
  const int rB = rA + 256;

  uint32_t wA[96], wB[96];
  {
    const uint4* gA = reinterpret_cast<const uint4*>(wpk + rA * 128);
    const uint4* gB = reinterpret_cast<const uint4*>(wpk + rB * 128);
#pragma unroll
    for (int q = 0; q < 24; ++q) {
      uint4 a = gA[q];
      wA[4 * q + 0] = a.x; wA[4 * q + 1] = a.y; wA[4 * q + 2] = a.z; wA[4 * q + 3] = a.w;
      uint4 b = gB[q];
      wB[4 * q + 0] = b.x; wB[4 * q + 1] = b.y; wB[4 * q + 2] = b.z; wB[4 * q + 3] = b.w;
    }
#pragma unroll
    for (int c = 0; c < 8; ++c) {
      wlds[(c * 2 + 0) * 512 + tid] = gA[24 + c];
      wlds[(c * 2 + 1) * 512 + tid] = gB[24 + c];
    }
  }
  if (tid < 256) hbuf[0][tid] = 0;
  __syncthreads();

  const int* mycnt = &cnt[(4 + (l - 1) * 2 + odd) * CNT_STRIDE];
  int rdy = 0;
  if (l) wait_ge(mycnt, 1, rdy);
  float c_ = 0.f;
  float xga = ldg_f32(xgsrc + rA), xgb = ldg_f32(xgsrc + rB);
  int pp = 0;
  for (int t = 0; t < 512; ++t) {
    const int tn = (t < 511) ? (t + 1) : 511;
    if (l) {
      int need = (t + 2 > 512) ? 512 : (t + 2);
      wait_ge(mycnt, need, rdy);
    }
    float nxa = ldg_f32(xgsrc + tn * 1024 + rA);  // prefetch t+1
    float nxb = ldg_f32(xgsrc + tn * 1024 + rB);

    float accA0 = xga, accA1 = 0.f, accB0 = xgb, accB1 = 0.f;
    const uint4* hv4 = reinterpret_cast<const uint4*>(&hbuf[pp][0]);
#pragma unroll
    for (int ch = 0; ch < 24; ++ch) {
      uint4 h4 = hv4[ch];
      accA0 = fdot2u(wA[4 * ch + 0], h4.x, accA0);
      accA1 = fdot2u(wA[4 * ch + 1], h4.y, accA1);
      accA0 = fdot2u(wA[4 * ch + 2], h4.z, accA0);
      accA1 = fdot2u(wA[4 * ch + 3], h4.w, accA1);
      accB0 = fdot2u(wB[4 * ch + 0], h4.x, accB0);
      accB1 = fdot2u(wB[4 * ch + 1], h4.y, accB1);
      accB0 = fdot2u(wB[4 * ch + 2], h4.z, accB0);
      accB1 = fdot2u(wB[4 * ch + 3], h4.w, accB1);
    }
#pragma unroll
    for (int cc = 0; cc < 8; ++cc) {
      uint4 h4 = hv4[24 + cc];
      uint4 wa = wlds[(cc * 2 + 0) * 512 + tid];
      uint4 wb = wlds[(cc * 2 + 1) * 512 + tid];
      accA0 = fdot2u(wa.x, h4.x, accA0);
      accA1 = fdot2u(wa.y, h4.y, accA1);
      accA0 = fdot2u(wa.z, h4.z, accA0);
      accA1 = fdot2u(wa.w, h4.w, accA1);
      accB0 = fdot2u(wb.x, h4.x, accB0);
      accB1 = fdot2u(wb.y, h4.y, accB1);
      accB0 = fdot2u(wb.z, h4.z, accB0);
      accB1 = fdot2u(wb.w, h4.w, accB1);
    }
    float accA = accA0 + accA1;
    float accB = accB0 + accB1;

    float o0 = __shfl_xor(accA, 1);
    float o1 = __shfl_xor(accB, 1);
    float pi = odd ? o0 : accA;
    float pf = odd ? o1 : accB;
    float pg = odd ? accA : o0;
    float po = odd ? accB : o1;

    c_ = sigmoidf_(pf) * c_ + sigmoidf_(pi) * tanhf_(pg);
    float h = sigmoidf_(po) * tanhf_(c_);
    if (!odd) {
      stg_f32(hseq + t * 256 + j, h);  // device-coherent store
      union { _Float16 hf; uint16_t u; } cv;
      cv.hf = (_Float16)h;
      hbuf[pp ^ 1][j] = cv.u;
    }
    __syncthreads();  // vmcnt(0) drain -> h stores at coherence point
    if (tid == 0) cnt_store(&cnt[l * CNT_STRIDE], t + 1);
    pp ^= 1;
    xga = nxa;
    xgb = nxb;
  }
}

// proj: 512 thr, WG owns rows [half*512, half*512+512), 1 row/thread.
// 4-step chunks: one poll + one batched h-load RTT + one store-drain RTT
// amortize over 4 steps -> ~1800cy/step, below scan rate.
__device__ void proj_fn(int l, int half, const uint32_t* __restrict__ wpk,
                        const float* __restrict__ bih, const float* __restrict__ bhh,
                        const float* __restrict__ hsrc,   // hseq layer l-1 (f32)
                        float* __restrict__ xgdst, int* __restrict__ cnt) {
  __shared__ __align__(16) uint32_t hpk[4][128];  // 4 steps of packed fp16 h
  const int tid = threadIdx.x;
  const int row = half * 512 + tid;

  uint32_t wr_[128];
  {
    const uint4* g = reinterpret_cast<const uint4*>(wpk + (size_t)row * 128);
#pragma unroll
    for (int q = 0; q < 32; ++q) {
      uint4 v = g[q];
      wr_[4 * q + 0] = v.x; wr_[4 * q + 1] = v.y; wr_[4 * q + 2] = v.z; wr_[4 * q + 3] = v.w;
    }
  }
  const float bias = bih[row] + bhh[row];
  const int* prev = &cnt[(l - 1) * CNT_STRIDE];
  int* mine = &cnt[(4 + (l - 1) * 2 + half) * CNT_STRIDE];
  int rdy = 0;
  const int s4 = tid >> 7;    // pack slot 0..3 (step within chunk)
  const int c4 = tid & 127;   // column pair

  for (int tt = 0; tt < 128; ++tt) {
    const int t0 = tt * 4;
    wait_ge(prev, t0 + 4, rdy);  // h(t0..t0+3) visible
    {
      uint64_t hv = ldg_u64(hsrc + (t0 + s4) * 256 + 2 * c4);  // one RTT, batched
      float hx = __builtin_bit_cast(float, (uint32_t)hv);
      float hy = __builtin_bit_cast(float, (uint32_t)(hv >> 32));
      union { _Float16 h; uint16_t u; } a, b;
      a.h = (_Float16)hx;
      b.h = (_Float16)hy;
      hpk[s4][c4] = (uint32_t)a.u | ((uint32_t)b.u << 16);
    }
    __syncthreads();  // 4 steps of h staged
#pragma unroll
    for (int s = 0; s < 4; ++s) {
      float a0 = bias, a1 = 0.f;
      const uint4* hv4 = reinterpret_cast<const uint4*>(hpk[s]);
#pragma unroll
      for (int q = 0; q < 32; ++q) {
        uint4 h4 = hv4[q];
        a0 = fdot2u(wr_[4 * q + 0], h4.x, a0);
        a1 = fdot2u(wr_[4 * q + 1], h4.y, a1);
        a0 = fdot2u(wr_[4 * q + 2], h4.z, a0);
        a1 = fdot2u(wr_[4 * q + 3], h4.w, a1);
      }
      stg_f32(xgdst + (t0 + s) * 1024 + row, a0 + a1);
    }
    __syncthreads();  // all 4 xg stores drained; hpk reads done
    if (tid == 0) cnt_store(mine, t0 + 4);  // xg(0..t0+3) ready
  }
}

// final linear, fused: streams cnt[3]. 2 threads/row, f32 weights in regs.
__device__ void final_fn(const float* __restrict__ lrw, const float* __restrict__ lrb,
                         const float* __restrict__ h3, float* __restrict__ out,
                         const int* __restrict__ cnt) {
  __shared__ __align__(16) float hs[256];
  const int tid = threadIdx.x;
  const int row = tid >> 1;   // 0..255
  const int kh = tid & 1;     // k-half
  float w_[128];
  {
    const float4* g = reinterpret_cast<const float4*>(lrw + (size_t)row * 256 + kh * 128);
#pragma unroll
    for (int q = 0; q < 32; ++q) {
      float4 v = g[q];
      w_[4 * q + 0] = v.x; w_[4 * q + 1] = v.y; w_[4 * q + 2] = v.z; w_[4 * q + 3] = v.w;
    }
  }
  const float bias = lrb[row];
  const int* prev = &cnt[3 * CNT_STRIDE];
  int rdy = 0;
  for (int t = 0; t < 512; ++t) {
    wait_ge(prev, t + 1, rdy);
    if (tid < 128) {
      uint64_t hv = ldg_u64(h3 + t * 256 + 2 * tid);  // device-coherent 8B
      hs[2 * tid] = __builtin_bit_cast(float, (uint32_t)hv);
      hs[2 * tid + 1] = __builtin_bit_cast(float, (uint32_t)(hv >> 32));
    }
    __syncthreads();
    float a0 = 0.f, a1 = 0.f;
    const float* hp = hs + kh * 128;
#pragma unroll
    for (int k = 0; k < 128; k += 4) {
      a0 += w_[k] * hp[k] + w_[k + 2] * hp[k + 2];
      a1 += w_[k + 1] * hp[k + 1] + w_[k + 3] * hp[k + 3];
    }
    float s = a0 + a1;
    s += __shfl_xor(s, 1);  // combine k-halves
    if (!kh) out[t * 256 + row] = s + bias;  // plain store, d_out
    __syncthreads();  // hs reads done before next overwrite
  }
}

// grid.x = 11:
// 0=scan0 | 1,2=proj1 | 3=scan1 | 4,5=proj2 | 6=scan2 | 7,8=proj3 | 9=scan3 | 10=final
__global__ __launch_bounds__(512, 2) void pipeline(
    const uint32_t* __restrict__ wpkhh, const uint32_t* __restrict__ wpkih,
    const float* __restrict__ xg0, float* __restrict__ xgp,
    float* __restrict__ hseq,
    const float* __restrict__ bih1, const float* __restrict__ bhh1,
    const float* __restrict__ bih2, const float* __restrict__ bhh2,
    const float* __restrict__ bih3, const float* __restrict__ bhh3,
    const float* __restrict__ lrw, const float* __restrict__ lrb,
    float* __restrict__ out, int* __restrict__ cnt) {
  const int bx = blockIdx.x;
  if (bx == 0) {
    scan_fn(0, wpkhh, xg0, hseq, cnt);
  } else if (bx == 10) {
    final_fn(lrw, lrb, hseq + (size_t)3 * 131072, out, cnt);
  } else {
    const int g = bx - 1;
    const int l = g / 3 + 1;
    const int r = g % 3;
    const float* bih = (l == 1) ? bih1 : (l == 2) ? bih2 : bih3;
    const float* bhh = (l == 1) ? bhh1 : (l == 2) ? bhh2 : bhh3;
    if (r < 2)
      proj_fn(l, r, wpkih + (size_t)(l - 1) * 131072, bih, bhh,
              hseq + (size_t)(l - 1) * 131072, xgp + (size_t)(l - 1) * 524288, cnt);
    else
      scan_fn(l, wpkhh + (size_t)l * 131072, xgp + (size_t)(l - 1) * 524288,
              hseq + (size_t)l * 131072, cnt);
  }
}

extern "C" void kernel_launch(void* const* d_in, const int* in_sizes, int n_in,
                              void* d_out, int out_size, void* d_ws, size_t ws_size,
                              hipStream_t stream) {
  (void)in_sizes; (void)n_in; (void)out_size; (void)ws_size;
  const float* x = (const float*)d_in[0];
  const float* wih[4] = {(const float*)d_in[1], (const float*)d_in[5],
                         (const float*)d_in[9], (const float*)d_in[13]};
  const float* whh[4] = {(const float*)d_in[2], (const float*)d_in[6],
                         (const float*)d_in[10], (const float*)d_in[14]};
  const float* bih[4] = {(const float*)d_in[3], (const float*)d_in[7],
                         (const float*)d_in[11], (const float*)d_in[15]};
  const float* bhh[4] = {(const float*)d_in[4], (const float*)d_in[8],
                         (const float*)d_in[12], (const float*)d_in[16]};
  const float* lrw = (const float*)d_in[17];
  const float* lrb = (const float*)d_in[18];
  float* out = (float*)d_out;

  // ws layout (4B units):
  //   xg0[524288] | xgp[3*524288] | hseq[4*131072] | wpkhh u32[4*131072]
  //   | wpkih u32[3*131072] | cnt int[16*CNT_STRIDE]      (~14.2 MB total)
  float* ws = (float*)d_ws;
  float* xg0 = ws;
  float* xgp = ws + 524288;
  float* hseq = xgp + 3 * 524288;
  uint32_t* wpkhh = (uint32_t*)(hseq + 4 * 131072);
  uint32_t* wpkih = wpkhh + 4 * 131072;
  int* cnt = (int*)(wpkih + 3 * 131072);

  zero_cnt<<<1, 512, 0, stream>>>(cnt);
  // one dispatch packs whh[0..3] then wih[1..3] into the contiguous region
  pack_all<<<3584, 256, 0, stream>>>(whh[0], whh[1], whh[2], whh[3],
                                     wih[1], wih[2], wih[3], wpkhh);

  // layer-0 projection from x (batch element 255)
  proj_gemm<<<dim3(4, 64), 256, 0, stream>>>(x + 255 * 512, 256 * 512, 512,
                                             wih[0], bih[0], bhh[0], xg0);

  pipeline<<<11, 512, 0, stream>>>(wpkhh, wpkih, xg0, xgp, hseq,
                                   bih[1], bhh[1], bih[2], bhh[2], bih[3], bhh[3],
                                   lrw, lrb, out, cnt);
}